// Round 1
// baseline (223.662 us; speedup 1.0000x reference)
//
#include <hip/hip_runtime.h>
#include <math.h>

// DetectionLoss: per-image Hungarian matching (JV shortest augmenting path,
// float64, transposed to 50 rows x 300 cols) + matched L1 / BCE losses.
// One wave (64 lanes) per image; 32 blocks. Latency-bound, not throughput.

#define BB 32
#define NN 300   // predictions (columns after transpose)
#define MM 50    // ground truths (rows after transpose)

__device__ __forceinline__ double softplus_d(double x) {
    // log(1+exp(x)) stable: max(x,0) + log1p(exp(-|x|))
    return fmax(x, 0.0) + log1p(exp(-fabs(x)));
}

__global__ __launch_bounds__(64) void lsa_loss_kernel(
    const float* __restrict__ pred_c,   // [B,N,2] f32
    const float* __restrict__ conf,     // [B,N]   f32
    const float* __restrict__ gt_c,     // [B,M,2] f32
    double* __restrict__ ws)            // [B,3] per-image partials
{
    const int b = blockIdx.x;
    const int lane = threadIdx.x;

    __shared__ double s_px[NN], s_py[NN], s_cneg[NN];   // f64 pred + (-sigmoid(conf))
    __shared__ double s_v[NN], s_shortest[NN];
    __shared__ int    s_pathback[NN], s_row4col[NN], s_remaining[NN];
    __shared__ double s_gx[MM], s_gy[MM], s_u[MM];
    __shared__ int    s_col4row[MM];

    // ---- load & init (f64, matching reference's np.float64 matching) ----
    for (int j = lane; j < NN; j += 64) {
        double px = (double)pred_c[(b*NN + j)*2 + 0];
        double py = (double)pred_c[(b*NN + j)*2 + 1];
        double cf = (double)conf[b*NN + j];
        s_px[j] = px; s_py[j] = py;
        s_cneg[j] = -(1.0 / (1.0 + exp(-cf)));   // COST_CONF * (-sigmoid)
        s_v[j] = 0.0;
        s_row4col[j] = -1;
    }
    if (lane < MM) {
        s_gx[lane] = (double)gt_c[(b*MM + lane)*2 + 0];
        s_gy[lane] = (double)gt_c[(b*MM + lane)*2 + 1];
        s_u[lane]  = 0.0;
        s_col4row[lane] = -1;
    }
    __syncthreads();

    // ---- JV shortest augmenting path over 50 rows ----
    for (int cur_row = 0; cur_row < MM; ++cur_row) {
        for (int j = lane; j < NN; j += 64) {
            s_shortest[j] = INFINITY;
            s_pathback[j] = -1;
            s_remaining[j] = 1;
        }
        __syncthreads();

        unsigned long long sr_mask = 0ull;   // uniform across lanes
        double min_val = 0.0;
        int i = cur_row;
        int sink = -1;

        while (sink < 0) {
            sr_mask |= (1ull << i);
            const double u_i = s_u[i];
            const double gx = s_gx[i], gy = s_gy[i];

            // relax: each lane owns columns lane+64k -> no cross-lane deps
            #pragma unroll
            for (int k = 0; k < 5; ++k) {
                int j = lane + 64*k;
                if (j < NN && s_remaining[j]) {
                    double cost = 5.0 * (fabs(s_px[j]-gx) + fabs(s_py[j]-gy)) + s_cneg[j];
                    double ncost = ((min_val + cost) - u_i) - s_v[j];
                    if (ncost < s_shortest[j]) { s_shortest[j] = ncost; s_pathback[j] = i; }
                }
            }
            __syncthreads();

            // argmin over remaining columns; ties -> smallest j (np.argmin semantics)
            double best = INFINITY; int bestj = 0x7fffffff;
            #pragma unroll
            for (int k = 0; k < 5; ++k) {
                int j = lane + 64*k;
                if (j < NN && s_remaining[j]) {
                    double sv = s_shortest[j];
                    if (sv < best) { best = sv; bestj = j; }
                }
            }
            #pragma unroll
            for (int off = 32; off > 0; off >>= 1) {
                double ob = __shfl_xor(best, off, 64);
                int    oj = __shfl_xor(bestj, off, 64);
                if (ob < best || (ob == best && oj < bestj)) { best = ob; bestj = oj; }
            }
            min_val = best;                        // uniform
            if (lane == 0) s_remaining[bestj] = 0;
            __syncthreads();

            int r4c = s_row4col[bestj];            // broadcast read
            if (r4c < 0) sink = bestj; else i = r4c;
        }

        // dual updates (before path backtrack, as in reference)
        if (lane < MM) {
            if (lane == cur_row) {
                s_u[lane] += min_val;
            } else if ((sr_mask >> lane) & 1ull) {
                s_u[lane] += min_val - s_shortest[s_col4row[lane]];
            }
        }
        #pragma unroll
        for (int k = 0; k < 5; ++k) {
            int j = lane + 64*k;
            if (j < NN && !s_remaining[j])         // SC = removed columns
                s_v[j] -= min_val - s_shortest[j];
        }
        __syncthreads();

        // augmenting-path backtrack (serial, lane 0; path is short)
        if (lane == 0) {
            int j = sink;
            while (1) {
                int pi = s_pathback[j];
                s_row4col[j] = pi;
                int nj = s_col4row[pi];
                s_col4row[pi] = j;
                j = nj;
                if (pi == cur_row) break;
            }
        }
        __syncthreads();
    }

    // ---- losses from f32 inputs (reference computes loss in f32/jnp) ----
    double lp = 0.0, lo = 0.0, ln = 0.0;
    if (lane < MM) {
        int j = s_col4row[lane];                   // matched pred for gt row `lane`
        float dx = fabsf(pred_c[(b*NN + j)*2 + 0] - gt_c[(b*MM + lane)*2 + 0]);
        float dy = fabsf(pred_c[(b*NN + j)*2 + 1] - gt_c[(b*MM + lane)*2 + 1]);
        lp = (double)dx + (double)dy;
        lo = softplus_d(-(double)conf[b*NN + j]);  // BCE target=1
    }
    #pragma unroll
    for (int k = 0; k < 5; ++k) {
        int j = lane + 64*k;
        if (j < NN && s_row4col[j] < 0)            // unmatched predictions
            ln += softplus_d((double)conf[b*NN + j]);
    }
    #pragma unroll
    for (int off = 32; off > 0; off >>= 1) {
        lp += __shfl_xor(lp, off, 64);
        lo += __shfl_xor(lo, off, 64);
        ln += __shfl_xor(ln, off, 64);
    }
    if (lane == 0) {
        ws[b*3 + 0] = lp / (double)(MM*2);   // per-image mean over (M,D)
        ws[b*3 + 1] = lo / (double)MM;       // per-image mean over M
        ws[b*3 + 2] = ln / (double)(NN-MM);  // sum / (N-M)
    }
}

__global__ __launch_bounds__(64) void finalize_kernel(
    const double* __restrict__ ws, float* __restrict__ out)
{
    int lane = threadIdx.x;
    double lp = 0.0, lo = 0.0, ln = 0.0;
    if (lane < BB) { lp = ws[lane*3+0]; lo = ws[lane*3+1]; ln = ws[lane*3+2]; }
    #pragma unroll
    for (int off = 32; off > 0; off >>= 1) {
        lp += __shfl_xor(lp, off, 64);
        lo += __shfl_xor(lo, off, 64);
        ln += __shfl_xor(ln, off, 64);
    }
    if (lane == 0) {
        double L_pos = 5.0 * lp / (double)BB;   // LAMBDA_POS * S / B
        double L_obj = 2.0 * lo / (double)BB;   // LAMBDA_CONF
        double L_no  = 0.5 * ln / (double)BB;   // LAMBDA_NOOBJ
        out[0] = (float)L_pos;
        out[1] = (float)L_obj;
        out[2] = (float)L_no;
        out[3] = (float)(L_pos + L_obj + L_no);
        out[4] = 50.0f;                          // n_matched = M
    }
}

extern "C" void kernel_launch(void* const* d_in, const int* in_sizes, int n_in,
                              void* d_out, int out_size, void* d_ws, size_t ws_size,
                              hipStream_t stream) {
    const float* pred_c = (const float*)d_in[0];   // [32,300,2]
    // d_in[1] = pred_logits (unused by reference)
    const float* conf   = (const float*)d_in[2];   // [32,300]
    const float* gt_c   = (const float*)d_in[3];   // [32,50,2]
    // d_in[4] = gt_classes (unused by reference)
    double* ws  = (double*)d_ws;                   // [32,3] partials
    float*  out = (float*)d_out;                   // 5 scalars

    lsa_loss_kernel<<<BB, 64, 0, stream>>>(pred_c, conf, gt_c, ws);
    finalize_kernel<<<1, 64, 0, stream>>>(ws, out);
}

// Round 2
// 162.352 us; speedup vs baseline: 1.3776x; 1.3776x over previous
//
#include <hip/hip_runtime.h>
#include <math.h>

// DetectionLoss: per-image Hungarian matching (JV shortest augmenting path,
// float64, transposed to 50 rows x 300 cols) + matched L1 / BCE losses.
// All-register design: one wave per image, columns j = 5*lane + k in
// registers (lanes 0..59), rows in lanes 0..49. No LDS, no __syncthreads.

#define BB 32
#define NN 300   // predictions (columns after transpose)
#define MM 50    // ground truths (rows after transpose)
#define KPL 5    // columns per lane (lanes 0..59 own 5 each: j = 5*lane+k)

__device__ __forceinline__ double softplus_d(double x) {
    // log(1+exp(x)) stable: max(x,0) + log1p(exp(-|x|))
    return fmax(x, 0.0) + log1p(exp(-fabs(x)));
}

// dynamic index into a length-5 register array -> unrolled cndmask chain
__device__ __forceinline__ int dynGetI(const int a[KPL], int q) {
    int r = a[0];
#pragma unroll
    for (int k = 1; k < KPL; ++k) if (q == k) r = a[k];
    return r;
}
__device__ __forceinline__ void dynSetI(int a[KPL], int q, int val) {
#pragma unroll
    for (int k = 0; k < KPL; ++k) if (q == k) a[k] = val;
}

__global__ __launch_bounds__(64) void lsa_loss_kernel(
    const float* __restrict__ pred_c,   // [B,N,2] f32
    const float* __restrict__ conf,     // [B,N]   f32
    const float* __restrict__ gt_c,     // [B,M,2] f32
    float* __restrict__ out)            // [5] f32, zeroed before launch
{
    const int b = blockIdx.x;
    const int lane = threadIdx.x;
    const bool owns = lane < (NN / KPL);   // lanes 0..59 own columns
    const int base_j = KPL * lane;

    // per-column state (registers)
    double px[KPL], py[KPL], cf[KPL], cneg[KPL], v[KPL], shortest[KPL];
    int pathback[KPL], row4col[KPL];
    int rem;
    // per-row state (lanes 0..49)
    double u = 0.0, gx = 0.0, gy = 0.0;
    int col4row = -1;

#pragma unroll
    for (int k = 0; k < KPL; ++k) {
        int j = base_j + k;
        if (owns) {
            px[k] = (double)pred_c[(b*NN + j)*2 + 0];
            py[k] = (double)pred_c[(b*NN + j)*2 + 1];
            cf[k] = (double)conf[b*NN + j];
        } else { px[k] = 0.0; py[k] = 0.0; cf[k] = 0.0; }
        cneg[k] = -(1.0 / (1.0 + exp(-cf[k])));   // COST_CONF * (-sigmoid)
        v[k] = 0.0;
        row4col[k] = -1;
    }
    if (lane < MM) {
        gx = (double)gt_c[(b*MM + lane)*2 + 0];
        gy = (double)gt_c[(b*MM + lane)*2 + 1];
    }

    for (int cur_row = 0; cur_row < MM; ++cur_row) {
#pragma unroll
        for (int k = 0; k < KPL; ++k) { shortest[k] = INFINITY; pathback[k] = -1; }
        rem = owns ? 0x1F : 0;
        unsigned long long sr_mask = 0ull;   // uniform
        double min_val = 0.0;
        int i = cur_row;
        int sink = -1;

        while (sink < 0) {
            sr_mask |= (1ull << i);
            double gx_i = __shfl(gx, i, 64);
            double gy_i = __shfl(gy, i, 64);
            double u_i  = __shfl(u,  i, 64);

            // relax owned remaining columns (pure registers)
#pragma unroll
            for (int k = 0; k < KPL; ++k) {
                if ((rem >> k) & 1) {
                    double cost = 5.0*(fabs(px[k]-gx_i)+fabs(py[k]-gy_i)) + cneg[k];
                    double nc = ((min_val + cost) - u_i) - v[k];
                    if (nc < shortest[k]) { shortest[k] = nc; pathback[k] = i; }
                }
            }

            // local argmin (k ascending, strict < -> smallest k on ties)
            double lbest = INFINITY; int lbestk = 0;
#pragma unroll
            for (int k = 0; k < KPL; ++k) {
                if (((rem >> k) & 1) && shortest[k] < lbest) { lbest = shortest[k]; lbestk = k; }
            }
            // value-only butterfly min; fmin returns an exact input value
            double gmin = lbest;
#pragma unroll
            for (int off = 32; off > 0; off >>= 1)
                gmin = fmin(gmin, __shfl_xor(gmin, off, 64));
            // lowest lane achieving gmin == smallest column index (contig map)
            unsigned long long mask = __ballot(lbest == gmin);
            int srcl = (int)__ffsll((unsigned long long)mask) - 1;
            int bestj = __shfl(base_j + lbestk, srcl, 64);
            min_val = gmin;   // uniform

            int tj = bestj / KPL, qj = bestj - KPL*tj;
            if (lane == tj) rem &= ~(1 << qj);
            int r4c_local = dynGetI(row4col, qj);
            int r4c = __shfl(r4c_local, tj, 64);
            if (r4c < 0) sink = bestj; else i = r4c;
        }

        // dual updates (before augment, as in reference)
        {
            int c  = col4row < 0 ? 0 : col4row;       // per-lane gather target
            int tc = c / KPL, qc = c - KPL*tc;
            double shc = 0.0;
#pragma unroll
            for (int k = 0; k < KPL; ++k) {
                double sk = __shfl(shortest[k], tc, 64);  // wave-wide, no divergence
                if (qc == k) shc = sk;
            }
            if (lane < MM) {
                if (lane == cur_row) u += min_val;
                else if ((sr_mask >> lane) & 1ull) u += min_val - shc;
            }
        }
#pragma unroll
        for (int k = 0; k < KPL; ++k) {
            if (owns && !((rem >> k) & 1))       // SC = columns removed this row
                v[k] -= min_val - shortest[k];
        }

        // augmenting-path backtrack (wave-uniform, shuffles only)
        int j = sink;
        while (true) {
            int tj = j / KPL, qj = j - KPL*tj;
            int pb_local = dynGetI(pathback, qj);
            int pi = __shfl(pb_local, tj, 64);
            if (lane == tj) dynSetI(row4col, qj, pi);
            int c_old = __shfl(col4row, pi, 64);
            if (lane == pi) col4row = j;
            j = c_old;
            if (pi == cur_row) break;
        }
    }

    // ---- losses from f32 inputs (reference computes loss in f32/jnp) ----
    double lp = 0.0, lo = 0.0, ln = 0.0;
    if (lane < MM) {
        int j = col4row;                         // matched pred for gt row `lane`
        float dx = fabsf(pred_c[(b*NN + j)*2 + 0] - gt_c[(b*MM + lane)*2 + 0]);
        float dy = fabsf(pred_c[(b*NN + j)*2 + 1] - gt_c[(b*MM + lane)*2 + 1]);
        lp = (double)dx + (double)dy;
        lo = softplus_d(-(double)conf[b*NN + j]);  // BCE target=1
    }
#pragma unroll
    for (int k = 0; k < KPL; ++k) {
        if (owns && row4col[k] < 0)              // unmatched predictions
            ln += softplus_d(cf[k]);
    }
#pragma unroll
    for (int off = 32; off > 0; off >>= 1) {
        lp += __shfl_xor(lp, off, 64);
        lo += __shfl_xor(lo, off, 64);
        ln += __shfl_xor(ln, off, 64);
    }
    if (lane == 0) {
        double cp = 5.0 * (lp / (double)(MM*2)) / (double)BB;   // LAMBDA_POS
        double co = 2.0 * (lo / (double)MM)    / (double)BB;    // LAMBDA_CONF
        double cn = 0.5 * (ln / (double)(NN-MM)) / (double)BB;  // LAMBDA_NOOBJ
        atomicAdd(&out[0], (float)cp);
        atomicAdd(&out[1], (float)co);
        atomicAdd(&out[2], (float)cn);
        atomicAdd(&out[3], (float)(cp + co + cn));
        if (b == 0) out[4] = 50.0f;              // n_matched = M
    }
}

extern "C" void kernel_launch(void* const* d_in, const int* in_sizes, int n_in,
                              void* d_out, int out_size, void* d_ws, size_t ws_size,
                              hipStream_t stream) {
    const float* pred_c = (const float*)d_in[0];   // [32,300,2]
    // d_in[1] = pred_logits (unused by reference)
    const float* conf   = (const float*)d_in[2];   // [32,300]
    const float* gt_c   = (const float*)d_in[3];   // [32,50,2]
    // d_in[4] = gt_classes (unused by reference)
    float* out = (float*)d_out;                    // 5 scalars

    hipMemsetAsync(out, 0, 5*sizeof(float), stream);   // d_out poisoned 0xAA
    lsa_loss_kernel<<<BB, 64, 0, stream>>>(pred_c, conf, gt_c, out);
}